// Round 1
// baseline (1159.841 us; speedup 1.0000x reference)
//
#include <hip/hip_runtime.h>
#include <stdint.h>
#include <math.h>

#define WIDTH  1024
#define HEIGHT 1024
#define DDIM   128
#define TOPK   2048
#define CAP    131072   // > 1024*1024/9 strict 5x5 maxima bound

// ---------------------------------------------------------------------------
// Kernel 1: 5x5 NMS -> compact (score,idx) candidates as 64-bit sort keys.
// key = (float_bits(score) << 32) | ~idx  -- scores > 0 so bits are monotone;
// descending key order == descending score, ties -> ascending idx (top_k tie rule).
// ---------------------------------------------------------------------------
__global__ void find_candidates(const float* __restrict__ feat,
                                const int* __restrict__ p_ow,
                                const int* __restrict__ p_oh,
                                unsigned int* __restrict__ counter,
                                unsigned long long* __restrict__ keys) {
    int x = blockIdx.x * blockDim.x + threadIdx.x;
    int y = blockIdx.y;
    const float* hm = feat + (size_t)DDIM * WIDTH * HEIGHT;
    float c = hm[y * WIDTH + x];
    if (!(c > 0.0f)) return;                    // mask: heatmap > 0 (also rejects NaN)
    int ow = p_ow[0], oh = p_oh[0];
    if (x > ow - 1 || y > oh - 1) return;       // in_bounds
    int y0 = max(y - 2, 0), y1 = min(y + 2, HEIGHT - 1);
    int x0 = max(x - 2, 0), x1 = min(x + 2, WIDTH - 1);
    float m = c;
    for (int yy = y0; yy <= y1; ++yy)
        for (int xx = x0; xx <= x1; ++xx)
            m = fmaxf(m, hm[yy * WIDTH + xx]);
    if (c == m) {                               // heatmap == pooled (SAME, clipped window)
        unsigned int pos = atomicAdd(counter, 1u);
        if (pos < CAP) {
            unsigned int idx = (unsigned int)(y * WIDTH + x);
            keys[pos] = ((unsigned long long)__float_as_uint(c) << 32)
                      | (unsigned long long)(~idx);
        }
    }
}

// ---------------------------------------------------------------------------
// Kernel 2: single block. Exact 64-bit radix-select of the TOPK-th key
// (6 passes x 11 bits), gather >= threshold into LDS, bitonic sort descending,
// write keypoints/scores/valid + selected idx list for the descriptor gather.
// ---------------------------------------------------------------------------
__global__ __launch_bounds__(1024) void select_topk(
        const unsigned int* __restrict__ counter,
        const unsigned long long* __restrict__ keys,
        float* __restrict__ out_kp,      // [TOPK][2]
        float* __restrict__ out_sc,      // [TOPK]
        float* __restrict__ out_vd,      // [TOPK]
        unsigned int* __restrict__ sel_idx) {
    __shared__ unsigned int hist[2048];
    __shared__ unsigned long long skeys[TOPK];
    __shared__ unsigned long long s_pval, s_pmask;
    __shared__ int s_k;
    __shared__ unsigned int s_sel;

    const int tid = threadIdx.x;
    const int nth = blockDim.x;
    unsigned int N = *counter;
    if (N > CAP) N = CAP;
    unsigned int KK = N < TOPK ? N : TOPK;     // (N >> TOPK in practice)

    if (tid == 0) { s_pval = 0ull; s_pmask = 0ull; s_k = (int)KK; s_sel = 0u; }
    __syncthreads();

    // ---- radix select on 64-bit keys: find the KK-th largest key exactly ----
    int shift = 64;
    while (shift > 0 && KK > 0) {
        int w = shift >= 11 ? 11 : shift;
        shift -= w;
        int bins = 1 << w;
        for (int b = tid; b < bins; b += nth) hist[b] = 0u;
        __syncthreads();
        unsigned long long pv = s_pval, pm = s_pmask;
        for (unsigned int i = tid; i < N; i += nth) {
            unsigned long long k = keys[i];
            if ((k & pm) == pv)
                atomicAdd(&hist[(unsigned int)(k >> shift) & (unsigned)(bins - 1)], 1u);
        }
        __syncthreads();
        if (tid == 0) {
            unsigned int cum = 0; int kk = s_k; int sel = 0;
            for (int b = bins - 1; b >= 0; --b) {
                unsigned int c = hist[b];
                if (cum + c >= (unsigned int)kk) { sel = b; s_k = kk - (int)cum; break; }
                cum += c;
            }
            s_pval = pv | ((unsigned long long)sel << shift);
            s_pmask = pm | ((unsigned long long)(bins - 1) << shift);
        }
        __syncthreads();
    }
    unsigned long long T = s_pval;   // exactly KK keys are >= T (keys are unique)

    // ---- gather the selected set into LDS (unordered) ----
    for (unsigned int i = tid; i < N; i += nth) {
        unsigned long long k = keys[i];
        if (k >= T) {
            unsigned int p = atomicAdd(&s_sel, 1u);
            if (p < TOPK) skeys[p] = k;
        }
    }
    __syncthreads();
    unsigned int M = s_sel < TOPK ? s_sel : TOPK;
    for (unsigned int i = M + tid; i < TOPK; i += nth) skeys[i] = 0ull;  // pad
    __syncthreads();

    // ---- bitonic sort, descending, 2048 elems, 1024 threads ----
    for (unsigned int size = 2; size <= TOPK; size <<= 1) {
        for (unsigned int strd = size >> 1; strd > 0; strd >>= 1) {
            for (unsigned int i = tid; i < TOPK; i += nth) {
                unsigned int j = i ^ strd;
                if (j > i) {
                    bool desc = ((i & size) == 0);
                    unsigned long long a = skeys[i], b = skeys[j];
                    if (desc ? (a < b) : (a > b)) { skeys[i] = b; skeys[j] = a; }
                }
            }
            __syncthreads();
        }
    }

    // ---- emit ----
    for (unsigned int r = tid; r < TOPK; r += nth) {
        unsigned long long k = skeys[r];
        bool live = (r < M);
        float score = __uint_as_float((unsigned int)(k >> 32));
        unsigned int idx = ~(unsigned int)(k & 0xFFFFFFFFull);
        unsigned int x = idx & (WIDTH - 1);
        unsigned int y = idx >> 10;
        out_kp[2 * r + 0] = live ? (float)x : 0.0f;
        out_kp[2 * r + 1] = live ? (float)y : 0.0f;
        out_sc[r] = live ? score : -INFINITY;
        out_vd[r] = live ? 1.0f : 0.0f;
        sel_idx[r] = live ? idx : 0u;
    }
}

// ---------------------------------------------------------------------------
// Kernel 3: descriptor gather + L2 normalize. One block per keypoint,
// 128 threads = 128 channels; wave shuffle + LDS combine for sum of squares.
// ---------------------------------------------------------------------------
__global__ __launch_bounds__(128) void gather_desc(
        const float* __restrict__ feat,
        const unsigned int* __restrict__ sel_idx,
        float* __restrict__ out_d) {
    int kp = blockIdx.x;
    int c  = threadIdx.x;
    unsigned int idx = sel_idx[kp];
    float v = feat[(size_t)c * (WIDTH * HEIGHT) + idx];
    float s = v * v;
    #pragma unroll
    for (int off = 32; off > 0; off >>= 1) s += __shfl_down(s, off, 64);
    __shared__ float sw[2];
    if ((c & 63) == 0) sw[c >> 6] = s;
    __syncthreads();
    float norm = sqrtf(sw[0] + sw[1]);
    norm = fmaxf(norm, 1e-12f);
    out_d[(size_t)kp * DDIM + c] = v / norm;
}

// ---------------------------------------------------------------------------
extern "C" void kernel_launch(void* const* d_in, const int* in_sizes, int n_in,
                              void* d_out, int out_size, void* d_ws, size_t ws_size,
                              hipStream_t stream) {
    const float* feat = (const float*)d_in[0];
    const int* p_ow = (const int*)d_in[1];
    const int* p_oh = (const int*)d_in[2];
    // d_in[3]=max_keypoints(2048), d_in[4]=window(5): baked into TOPK / radius 2.

    float* out = (float*)d_out;
    float* out_kp = out;                         // 2048*2
    float* out_sc = out + 2 * TOPK;              // 2048
    float* out_d  = out + 3 * TOPK;              // 2048*128
    float* out_vd = out + 3 * TOPK + TOPK * DDIM;// 2048

    unsigned int* counter = (unsigned int*)d_ws;
    unsigned long long* keys = (unsigned long long*)((char*)d_ws + 64);
    unsigned int* sel_idx = (unsigned int*)((char*)d_ws + 64 + (size_t)CAP * 8);

    hipMemsetAsync(d_ws, 0, 64, stream);         // zero candidate counter

    dim3 gridA(WIDTH / 256, HEIGHT);
    find_candidates<<<gridA, 256, 0, stream>>>(feat, p_ow, p_oh, counter, keys);
    select_topk<<<1, 1024, 0, stream>>>(counter, keys, out_kp, out_sc, out_vd, sel_idx);
    gather_desc<<<TOPK, DDIM, 0, stream>>>(feat, sel_idx, out_d);
}

// Round 2
// 697.021 us; speedup vs baseline: 1.6640x; 1.6640x over previous
//
#include <hip/hip_runtime.h>
#include <stdint.h>
#include <math.h>

#define WIDTH  1024
#define HEIGHT 1024
#define DDIM   128
#define TOPK   2048
#define CAP    131072     // > 1024*1024/9 strict 5x5 maxima bound
#define SELCAP 4096       // superset capacity: 2048 + boundary-bin (~300 expected)

// ---- workspace layout (bytes from d_ws) -----------------------------------
// hdr[0]=candidate count, hdr[1]=sel count, hdr[2]=threshold bin B, hdr[3]=KK
#define HIST_OFF 64
#define KEYS_OFF (HIST_OFF + 65536 * 4)          // 262208
#define SEL_OFF  (KEYS_OFF + CAP * 8)            // +1 MiB
#define SIDX_OFF (SEL_OFF + SELCAP * 8)          // +32 KiB; total ~1.3 MiB

// ---------------------------------------------------------------------------
// Kernel 1: 5x5 NMS via clamped (=clipped, duplicates don't change max) reads,
// 3x3 early exit. Per-row block: LDS candidate buffer -> ONE global atomic per
// block. Also builds 65536-bin histogram of key top-16 bits (sign+exp+7 mant).
// key = (score_bits<<32) | ~idx : monotone for score>0, ties -> ascending idx.
// ---------------------------------------------------------------------------
__global__ __launch_bounds__(1024) void find_candidates(
        const float* __restrict__ feat,
        const int* __restrict__ p_ow, const int* __restrict__ p_oh,
        unsigned int* __restrict__ hdr,
        unsigned int* __restrict__ hist,
        unsigned long long* __restrict__ keys) {
    const int x = threadIdx.x;
    const int y = blockIdx.x;
    const float* hm = feat + (size_t)DDIM * WIDTH * HEIGHT;

    __shared__ unsigned long long lkeys[256];
    __shared__ unsigned int lcnt, lbase;
    if (x == 0) lcnt = 0u;
    __syncthreads();

    float c = hm[y * WIDTH + x];
    // heatmap > 0 (rejects NaN too) & in_bounds
    if ((c > 0.0f) && (x <= p_ow[0] - 1) && (y <= p_oh[0] - 1)) {
        int xm2 = max(x - 2, 0), xm1 = max(x - 1, 0);
        int xp1 = min(x + 1, WIDTH - 1), xp2 = min(x + 2, WIDTH - 1);
        int ym2 = max(y - 2, 0), ym1 = max(y - 1, 0);
        int yp1 = min(y + 1, HEIGHT - 1), yp2 = min(y + 2, HEIGHT - 1);
        const float* r0 = hm + ym1 * WIDTH;
        const float* r1 = hm + y   * WIDTH;
        const float* r2 = hm + yp1 * WIDTH;
        // inner 3x3 ring first (8 loads) — rejects ~8/9 of positives
        float m = fmaxf(fmaxf(fmaxf(r0[xm1], r0[x]), fmaxf(r0[xp1], r1[xm1])),
                        fmaxf(fmaxf(r1[xp1], r2[xm1]), fmaxf(r2[x], r2[xp1])));
        if (m <= c) {
            const float* ra = hm + ym2 * WIDTH;
            const float* rb = hm + yp2 * WIDTH;
            float m2 = fmaxf(fmaxf(fmaxf(ra[xm2], ra[xm1]), fmaxf(ra[x], ra[xp1])), ra[xp2]);
            m2 = fmaxf(m2, fmaxf(fmaxf(rb[xm2], rb[xm1]), fmaxf(fmaxf(rb[x], rb[xp1]), rb[xp2])));
            m2 = fmaxf(m2, fmaxf(fmaxf(r0[xm2], r0[xp2]), fmaxf(r1[xm2], r1[xp2])));
            m2 = fmaxf(m2, fmaxf(r2[xm2], r2[xp2]));
            if (m2 <= c) {   // strict local max of clipped 5x5 window
                unsigned int idx = (unsigned int)(y * WIDTH + x);
                unsigned long long key =
                    ((unsigned long long)__float_as_uint(c) << 32) |
                    (unsigned long long)(~idx);
                unsigned int p = atomicAdd(&lcnt, 1u);
                if (p < 256u) lkeys[p] = key;
            }
        }
    }
    __syncthreads();
    if (x == 0) lbase = atomicAdd(&hdr[0], lcnt);
    __syncthreads();
    unsigned int n = lcnt < 256u ? lcnt : 256u;
    unsigned int base = lbase;
    for (unsigned int i = x; i < n; i += blockDim.x) {
        unsigned long long k = lkeys[i];
        if (base + i < CAP) keys[base + i] = k;
        atomicAdd(&hist[(unsigned int)(k >> 48)], 1u);
    }
}

// ---------------------------------------------------------------------------
// Kernel 2: one block. Parallel suffix-scan of the 65536-bin histogram
// (64 bins/thread + 10 log-steps) -> threshold bin B: count(keys in bins > B)
// < target <= count(keys in bins >= B). target = min(N, TOPK).
// ---------------------------------------------------------------------------
__global__ __launch_bounds__(1024) void scan_hist(
        unsigned int* __restrict__ hdr,
        const unsigned int* __restrict__ hist) {
    __shared__ unsigned int part[1024];
    const int tid = threadIdx.x;
    const unsigned int base = (unsigned int)tid * 64u;
    unsigned int s = 0;
    #pragma unroll 8
    for (int j = 0; j < 64; ++j) s += hist[base + j];
    part[tid] = s;
    __syncthreads();
    // inclusive suffix sums: part[t] = sum_{t' >= t} partial[t']
    for (int d = 1; d < 1024; d <<= 1) {
        unsigned int v = (tid + d < 1024) ? part[tid + d] : 0u;
        __syncthreads();
        part[tid] += v;
        __syncthreads();
    }
    unsigned int N = hdr[0]; if (N > CAP) N = CAP;
    unsigned int target = N < TOPK ? N : TOPK;
    if (tid == 0) { hdr[3] = target; if (target == 0) hdr[2] = 0u; }
    if (target == 0) return;
    unsigned int St = part[tid];
    unsigned int Sn = (tid < 1023) ? part[tid + 1] : 0u;
    if (St >= target && Sn < target) {          // exactly one thread
        unsigned int above = Sn;
        unsigned int B = base;
        for (int b = (int)base + 63; b >= (int)base; --b) {
            unsigned int h = hist[b];
            if (above + h >= target) { B = (unsigned int)b; break; }
            above += h;
        }
        hdr[2] = B;
    }
}

// ---------------------------------------------------------------------------
// Kernel 3: compact keys with top16 >= B (superset of exact top-K, ~2.3K keys)
// ---------------------------------------------------------------------------
__global__ void filter_keys(unsigned int* __restrict__ hdr,
                            const unsigned long long* __restrict__ keys,
                            unsigned long long* __restrict__ sel) {
    unsigned int N = hdr[0]; if (N > CAP) N = CAP;
    unsigned long long B = (unsigned long long)hdr[2];
    unsigned int stride = gridDim.x * blockDim.x;
    for (unsigned int i = blockIdx.x * blockDim.x + threadIdx.x; i < N; i += stride) {
        unsigned long long k = keys[i];
        if ((k >> 48) >= B) {
            unsigned int p = atomicAdd(&hdr[1], 1u);
            if (p < SELCAP) sel[p] = k;
        }
    }
}

// ---------------------------------------------------------------------------
// Kernel 4: one block. Bitonic sort SELCAP keys (0-padded) descending in LDS,
// emit exact top-TOPK: keypoints, scores, valid, and idx list for the gather.
// ---------------------------------------------------------------------------
__global__ __launch_bounds__(1024) void sort_emit(
        const unsigned int* __restrict__ hdr,
        const unsigned long long* __restrict__ sel,
        float* __restrict__ out_kp, float* __restrict__ out_sc,
        float* __restrict__ out_vd, unsigned int* __restrict__ sidx) {
    __shared__ unsigned long long sk[SELCAP];
    const int tid = threadIdx.x;
    unsigned int M = hdr[1]; if (M > SELCAP) M = SELCAP;
    unsigned int KK = hdr[3];                    // min(N, TOPK); M >= KK always
    for (unsigned int i = tid; i < SELCAP; i += 1024) sk[i] = (i < M) ? sel[i] : 0ull;
    __syncthreads();
    for (unsigned int size = 2; size <= SELCAP; size <<= 1) {
        for (unsigned int str = size >> 1; str > 0; str >>= 1) {
            for (unsigned int i = tid; i < SELCAP; i += 1024) {
                unsigned int j = i ^ str;
                if (j > i) {
                    unsigned long long a = sk[i], b = sk[j];
                    bool desc = ((i & size) == 0);
                    if (desc ? (a < b) : (a > b)) { sk[i] = b; sk[j] = a; }
                }
            }
            __syncthreads();
        }
    }
    for (unsigned int r = tid; r < TOPK; r += 1024) {
        unsigned long long k = sk[r];
        bool live = (r < KK);
        unsigned int idx = ~(unsigned int)(k & 0xFFFFFFFFull);
        out_kp[2 * r + 0] = live ? (float)(idx & (WIDTH - 1)) : 0.0f;
        out_kp[2 * r + 1] = live ? (float)(idx >> 10) : 0.0f;
        out_sc[r] = live ? __uint_as_float((unsigned int)(k >> 32)) : -INFINITY;
        out_vd[r] = live ? 1.0f : 0.0f;
        sidx[r]   = live ? idx : 0u;
    }
}

// ---------------------------------------------------------------------------
// Kernel 5: descriptor gather + L2 normalize. One block/keypoint, 128 ch.
// ---------------------------------------------------------------------------
__global__ __launch_bounds__(128) void gather_desc(
        const float* __restrict__ feat,
        const unsigned int* __restrict__ sidx,
        float* __restrict__ out_d) {
    int kp = blockIdx.x;
    int c  = threadIdx.x;
    unsigned int idx = sidx[kp];
    float v = feat[(size_t)c * (WIDTH * HEIGHT) + idx];
    float s = v * v;
    #pragma unroll
    for (int off = 32; off > 0; off >>= 1) s += __shfl_down(s, off, 64);
    __shared__ float sw[2];
    if ((c & 63) == 0) sw[c >> 6] = s;
    __syncthreads();
    float norm = fmaxf(sqrtf(sw[0] + sw[1]), 1e-12f);
    out_d[(size_t)kp * DDIM + c] = v / norm;
}

// ---------------------------------------------------------------------------
extern "C" void kernel_launch(void* const* d_in, const int* in_sizes, int n_in,
                              void* d_out, int out_size, void* d_ws, size_t ws_size,
                              hipStream_t stream) {
    const float* feat = (const float*)d_in[0];
    const int* p_ow = (const int*)d_in[1];
    const int* p_oh = (const int*)d_in[2];
    // d_in[3]=max_keypoints(2048), d_in[4]=window(5): baked into TOPK / radius 2.

    float* out = (float*)d_out;
    float* out_kp = out;                              // 2048*2
    float* out_sc = out + 2 * TOPK;                   // 2048
    float* out_d  = out + 3 * TOPK;                   // 2048*128
    float* out_vd = out + 3 * TOPK + TOPK * DDIM;     // 2048

    unsigned int* hdr  = (unsigned int*)d_ws;
    unsigned int* hist = (unsigned int*)((char*)d_ws + HIST_OFF);
    unsigned long long* keys = (unsigned long long*)((char*)d_ws + KEYS_OFF);
    unsigned long long* sel  = (unsigned long long*)((char*)d_ws + SEL_OFF);
    unsigned int* sidx = (unsigned int*)((char*)d_ws + SIDX_OFF);

    hipMemsetAsync(d_ws, 0, KEYS_OFF, stream);        // hdr + 256 KiB histogram

    find_candidates<<<HEIGHT, 1024, 0, stream>>>(feat, p_ow, p_oh, hdr, hist, keys);
    scan_hist<<<1, 1024, 0, stream>>>(hdr, hist);
    filter_keys<<<128, 256, 0, stream>>>(hdr, keys, sel);
    sort_emit<<<1, 1024, 0, stream>>>(hdr, sel, out_kp, out_sc, out_vd, sidx);
    gather_desc<<<TOPK, DDIM, 0, stream>>>(feat, sidx, out_d);
}